// Round 7
// baseline (204.949 us; speedup 1.0000x reference)
//
#include <hip/hip_runtime.h>

typedef unsigned int u32;

static constexpr int HH = 1080, WW = 1920;
static constexpr int NPIX = HH * WW;            // 2,073,600
static constexpr int NQ = 17;                   // supports split <= 16 (actual 10)
static constexpr int MAXOWN = 15;               // max distinct quantile hi-12 bins (60 KB LDS)
static constexpr int NBLK = 256;                // grid for histA / ph2 / scatter (must match!)
static constexpr int R1 = 16;                   // replicas for level-1 bin merge
static constexpr int NCH1 = 64;                 // chunks for ph1
static constexpr int TS = 64;                   // target tile size
static constexpr int TCX = WW / TS;             // 30
static constexpr int TCY = (HH + TS - 1) / TS;  // 17
static constexpr int NTILE = TCX * TCY;         // 510 (padded to 512)
static constexpr int NT512 = 512;

// ---- workspace layout (bytes) ----
static constexpr size_t MIDS_OFF  = 0;     // float[32]
static constexpr size_t QB1_OFF   = 128;   // u32[32]
static constexpr size_t QR1_OFF   = 256;   // u32[32]
static constexpr size_t OIDX_OFF  = 384;   // u32[32]  query -> owner index
static constexpr size_t OBIN_OFF  = 512;   // u32[32]  owner -> hi-12 bin
static constexpr size_t NOWN_OFF  = 640;   // u32[1]
static constexpr size_t KEY22_OFF = 768;   // u32[32]  query -> 22-bit prefix
static constexpr size_t R2O_OFF   = 896;   // u32[32]  rank within 22-bit bin
static constexpr size_t TOT1_OFF  = 1024;                                   // u32[R1*4096]
static constexpr size_t GH2_OFF   = TOT1_OFF + (size_t)R1 * 4096 * 4;       // u32[NQ*1024]
static constexpr size_t ZERO_BYTES = GH2_OFF + (size_t)NQ * 1024 * 4;       // ~333 KB
static constexpr size_t TCNT_OFF  = ZERO_BYTES;                             // u32[NBLK*512] fully written
static constexpr size_t TTOT_OFF  = TCNT_OFF + (size_t)NBLK * NT512 * 4;    // u32[512]
static constexpr size_t TBASE_OFF = TTOT_OFF + NT512 * 4;                   // u32[512]
static constexpr size_t TEND_OFF  = TBASE_OFF + NT512 * 4;                  // u32[512]
static constexpr size_t BASE2_OFF = TEND_OFF + NT512 * 4;                   // u32[512*NBLK]
static constexpr size_t GH1_OFF   = BASE2_OFF + (size_t)NT512 * NBLK * 4;   // u32[NQ*NCH1*1024]
static constexpr size_t PAIRS_OFF = GH1_OFF + (size_t)NQ * NCH1 * 1024 * 4; // uint2[NPIX]

// ---- geometry helper: target pixel index, or -1 if dropped (flow-only) ----
__device__ __forceinline__ int target_of(int y, int x, float fx, float fy) {
    int ty = (int)rintf((float)y + fy);  // rintf = round-half-even = jnp.round
    int tx = (int)rintf((float)x + fx);
    if (ty < 0) ty += HH;                // JAX normalizes negative indices once
    if (tx < 0) tx += WW;
    if ((unsigned)ty >= (unsigned)HH || (unsigned)tx >= (unsigned)WW) return -1;
    return ty * WW + tx;
}

// ---- level 1: LDS 4096-bin histogram of bits[31:20] + per-(block,tile) target counts ----
__global__ __launch_bounds__(256) void k_histA_cnt(const float* __restrict__ depth,
                                                   const float* __restrict__ flow,
                                                   u32* __restrict__ tot1,
                                                   u32* __restrict__ tcnt) {
    __shared__ u32 h[4096];
    __shared__ u32 tc[NT512];
    for (int j = threadIdx.x; j < 4096; j += 256) h[j] = 0;
    for (int j = threadIdx.x; j < NT512; j += 256) tc[j] = 0;
    __syncthreads();
    const int nvec = NPIX / 4;
    for (int v = blockIdx.x * 256 + threadIdx.x; v < nvec; v += gridDim.x * 256) {
        int i = v * 4;
        float4 d4 = ((const float4*)depth)[v];
        float4 fa = ((const float4*)flow)[v * 2];
        float4 fb = ((const float4*)flow)[v * 2 + 1];
        int y = i / WW, x0 = i - y * WW;   // 4-group never crosses a row (WW%4==0)
        float dd[4] = {d4.x, d4.y, d4.z, d4.w};
        float fx[4] = {fa.x, fa.z, fb.x, fb.z};
        float fy[4] = {fa.y, fa.w, fb.y, fb.w};
        #pragma unroll
        for (int j = 0; j < 4; ++j) {
            if (dd[j] != 100.0f)                                   // sentinel excluded
                atomicAdd(&h[__float_as_uint(dd[j]) >> 20], 1u);   // d>0 -> monotonic bits
            int t = target_of(y, x0 + j, fx[j], fy[j]);
            if (t >= 0) {
                int ty = t / WW, tx = t - ty * WW;
                atomicAdd(&tc[(ty >> 6) * TCX + (tx >> 6)], 1u);
            }
        }
    }
    __syncthreads();
    u32 rep = blockIdx.x & (R1 - 1);
    for (int j = threadIdx.x; j < 4096; j += 256) {
        u32 v = h[j];
        if (v) atomicAdd(&tot1[rep * 4096 + j], v);   // short chains (<=16/address)
    }
    for (int j = threadIdx.x; j < NT512; j += 256)
        tcnt[blockIdx.x * NT512 + j] = tc[j];         // non-atomic per-block counts
}

// ---- per-tile totals: reduce tcnt over blocks ----
__global__ __launch_bounds__(256) void k_tsum(const u32* __restrict__ tcnt,
                                              u32* __restrict__ ttot) {
    __shared__ u32 s[256];
    int t = blockIdx.x, tid = threadIdx.x;
    s[tid] = tcnt[tid * NT512 + t];
    __syncthreads();
    for (int off = 128; off > 0; off >>= 1) {
        if (tid < off) s[tid] += s[tid + off];
        __syncthreads();
    }
    if (tid == 0) ttot[t] = s[0];
}

// ---- level-1 select + owner table + tile-total prefix sum ----
__global__ __launch_bounds__(1024) void k_selA(const u32* __restrict__ tot1,
                                               const int* __restrict__ splitp,
                                               const u32* __restrict__ ttot,
                                               u32* __restrict__ qb1, u32* __restrict__ qr1,
                                               u32* __restrict__ oidx, u32* __restrict__ obin,
                                               u32* __restrict__ nown,
                                               u32* __restrict__ tbase, u32* __restrict__ tend) {
    __shared__ u32 part[1024];
    __shared__ u32 qbS[NQ], qcS[NQ];
    __shared__ u32 totalsh;
    int tid = threadIdx.x;
    int split = *splitp;
    int base = tid * 4;
    u32 cc[4] = {0, 0, 0, 0};
    for (int r = 0; r < R1; ++r)
        for (int j = 0; j < 4; ++j) cc[j] += tot1[r * 4096 + base + j];
    u32 local = cc[0] + cc[1] + cc[2] + cc[3];
    part[tid] = local;
    __syncthreads();
    for (int off = 1; off < 1024; off <<= 1) {
        u32 v = (tid >= off) ? part[tid - off] : 0;
        __syncthreads();
        part[tid] += v;
        __syncthreads();
    }
    if (tid == 1023) totalsh = part[1023];
    __syncthreads();
    u32 l = totalsh;                 // valid-pixel count = histogram sum
    u32 step = l / (u32)split;
    u32 cum = part[tid] - local;     // exclusive prefix of this thread's 4 bins
    for (int j = 0; j < 4; ++j) {
        u32 c = cc[j];
        if (c) {
            for (int q = 0; q <= split; ++q) {
                u32 r = (q < split) ? (u32)q * step : l - 1u;
                if (r >= cum && r < cum + c) {
                    qb1[q] = (u32)(base + j);
                    qr1[q] = r - cum;
                    qbS[q] = (u32)(base + j);
                    qcS[q] = c;
                }
            }
        }
        cum += c;
    }
    __syncthreads();
    if (tid == 0) {   // owners: distinct (adjacent, ascending) hi-12 bins
        int w = -1;
        u32 prev = 0xFFFFFFFFu;
        for (int q = 0; q <= split; ++q) {
            if (qbS[q] != prev) { ++w; prev = qbS[q]; obin[w] = qbS[q]; }
            oidx[q] = (u32)w;
        }
        *nown = (u32)(w + 1);
    }
    __syncthreads();
    // ---- tile totals prefix sum -> tbase/tend ----
    u32 tv = (tid < NT512) ? ttot[tid] : 0;
    part[tid] = tv;
    __syncthreads();
    for (int off = 1; off < 1024; off <<= 1) {
        u32 v = (tid >= off) ? part[tid - off] : 0;
        __syncthreads();
        part[tid] += v;
        __syncthreads();
    }
    if (tid < NT512) {
        tbase[tid] = part[tid] - tv;
        tend[tid]  = part[tid];
    }
}

// ---- per-(tile, block) exact write bases: scan tcnt along blocks ----
__global__ __launch_bounds__(256) void k_tscan(const u32* __restrict__ tcnt,
                                               const u32* __restrict__ tbase,
                                               u32* __restrict__ base2) {
    __shared__ u32 s[256];
    int t = blockIdx.x, b = threadIdx.x;
    u32 v = tcnt[b * NT512 + t];
    s[b] = v;
    __syncthreads();
    for (int off = 1; off < 256; off <<= 1) {
        u32 x = (b >= off) ? s[b - off] : 0;
        __syncthreads();
        s[b] += x;
        __syncthreads();
    }
    base2[t * NBLK + b] = tbase[t] + s[b] - v;   // exclusive prefix
}

// ---- level 2: per-owner LDS hist of bits[19:10] over contiguous depth chunks ----
__global__ __launch_bounds__(1024) void k_ph1(const float* __restrict__ depth,
                                              const u32* __restrict__ obin,
                                              const u32* __restrict__ nownp,
                                              u32* __restrict__ ghist) {
    __shared__ u32 h[MAXOWN * 1024];   // 60 KB
    __shared__ u32 ob[MAXOWN];
    int tid = threadIdx.x, c = blockIdx.x;
    int nown = (int)*nownp;
    if (nown > MAXOWN) nown = MAXOWN;
    if (tid < MAXOWN) ob[tid] = (tid < nown) ? obin[tid] : 0xFFFFFFFFu;
    for (int j = tid; j < nown * 1024; j += 1024) h[j] = 0;
    __syncthreads();
    const int per = (NPIX / 4) / NCH1;   // 8100 float4 per chunk, exact
    int lo = c * per, hi = lo + per;
    for (int v = lo + tid; v < hi; v += 1024) {
        float4 d4 = ((const float4*)depth)[v];
        float dd[4] = {d4.x, d4.y, d4.z, d4.w};
        #pragma unroll
        for (int j = 0; j < 4; ++j) {
            if (dd[j] != 100.0f) {
                u32 bits = __float_as_uint(dd[j]);
                u32 b1 = bits >> 20;
                for (int w = 0; w < nown; ++w)
                    if (ob[w] == b1) { atomicAdd(&h[w * 1024 + ((bits >> 10) & 1023u)], 1u); break; }
            }
        }
    }
    __syncthreads();
    for (int j = tid; j < nown * 1024; j += 1024) {
        int w = j >> 10, bin = j & 1023;
        ghist[(w * NCH1 + c) * 1024 + bin] = h[j];   // non-atomic chunk write
    }
}

// ---- level-2 reduce: chunks -> (key22, r2) per query ----
__global__ __launch_bounds__(1024) void k_red1(const int* __restrict__ splitp,
                                               const u32* __restrict__ qb1,
                                               const u32* __restrict__ qr1,
                                               const u32* __restrict__ oidx,
                                               const u32* __restrict__ ghist,
                                               u32* __restrict__ key22, u32* __restrict__ r2o) {
    int q = blockIdx.x;
    if (q > *splitp) return;
    int w = (int)oidx[q];
    __shared__ u32 part[1024];
    int tid = threadIdx.x;
    u32 local = 0;
    for (int c = 0; c < NCH1; ++c) local += ghist[(w * NCH1 + c) * 1024 + tid];
    part[tid] = local;
    __syncthreads();
    for (int off = 1; off < 1024; off <<= 1) {
        u32 v = (tid >= off) ? part[tid - off] : 0;
        __syncthreads();
        part[tid] += v;
        __syncthreads();
    }
    u32 target = qr1[q];
    u32 cum = part[tid] - local;
    if (local && target >= cum && target < cum + local) {
        key22[q] = (qb1[q] << 10) | (u32)tid;
        r2o[q] = target - cum;
    }
}

// ---- level 3: low-10-bit histogram restricted to 22-bit keys (tiny atomic count) ----
__global__ __launch_bounds__(256) void k_ph2(const float* __restrict__ depth,
                                             const int* __restrict__ splitp,
                                             const u32* __restrict__ key22,
                                             u32* __restrict__ gh2) {
    __shared__ u32 k22[NQ];
    int tid = threadIdx.x, split = *splitp;
    if (tid < NQ) k22[tid] = (tid <= split) ? key22[tid] : 0xFFFFFFFFu;
    __syncthreads();
    const int nvec = NPIX / 4;
    for (int v = blockIdx.x * 256 + tid; v < nvec; v += gridDim.x * 256) {
        float4 d4 = ((const float4*)depth)[v];
        float dd[4] = {d4.x, d4.y, d4.z, d4.w};
        #pragma unroll
        for (int j = 0; j < 4; ++j) {
            if (dd[j] != 100.0f) {
                u32 bits = __float_as_uint(dd[j]);
                u32 hi22 = bits >> 10;
                for (int q = 0; q <= split; ++q)
                    if (k22[q] == hi22) atomicAdd(&gh2[q * 1024 + (bits & 1023u)], 1u);
            }
        }
    }
}

// ---- level-3 reduce: exact order-statistic floats ----
__global__ __launch_bounds__(1024) void k_red2(const int* __restrict__ splitp,
                                               const u32* __restrict__ key22,
                                               const u32* __restrict__ r2o,
                                               const u32* __restrict__ gh2,
                                               float* __restrict__ mids) {
    int q = blockIdx.x;
    if (q > *splitp) return;
    __shared__ u32 part[1024];
    int tid = threadIdx.x;
    u32 local = gh2[q * 1024 + tid];
    part[tid] = local;
    __syncthreads();
    for (int off = 1; off < 1024; off <<= 1) {
        u32 v = (tid >= off) ? part[tid - off] : 0;
        __syncthreads();
        part[tid] += v;
        __syncthreads();
    }
    u32 target = r2o[q];
    u32 cum = part[tid] - local;
    if (local && target >= cum && target < cum + local)
        mids[q] = __uint_as_float((key22[q] << 10) | (u32)tid);
}

// ---- scatter: exact-base pair writes, zero device atomics, no inner barriers ----
__global__ __launch_bounds__(256) void k_scatter(const float* __restrict__ depth,
                                                 const float* __restrict__ flow,
                                                 const int* __restrict__ splitp,
                                                 const float* __restrict__ mids,
                                                 const u32* __restrict__ base2,
                                                 uint2* __restrict__ pairs) {
    __shared__ u32 cur[NT512];
    __shared__ float msh[NQ];
    int tid = threadIdx.x, split = *splitp;
    if (tid < NQ) msh[tid] = (tid <= split) ? mids[tid] : 0.f;
    for (int j = tid; j < NT512; j += 256) cur[j] = base2[j * NBLK + blockIdx.x];
    __syncthreads();
    const int nvec = NPIX / 4;   // traversal MUST match k_histA_cnt exactly
    for (int v = blockIdx.x * 256 + tid; v < nvec; v += gridDim.x * 256) {
        int i = v * 4;
        float4 d4 = ((const float4*)depth)[v];
        float4 fa = ((const float4*)flow)[v * 2];
        float4 fb = ((const float4*)flow)[v * 2 + 1];
        int y = i / WW, x0 = i - y * WW;
        float dd[4] = {d4.x, d4.y, d4.z, d4.w};
        float fx[4] = {fa.x, fa.z, fb.x, fb.z};
        float fy[4] = {fa.y, fa.w, fb.y, fb.w};
        #pragma unroll
        for (int j = 0; j < 4; ++j) {
            int t = target_of(y, x0 + j, fx[j], fy[j]);
            if (t < 0) continue;                      // only drop counted by histA too
            float d = dd[j];
            int rank = -1;
            for (int k = 1; k <= split; ++k)
                if (d >= msh[k - 1] && d < msh[k]) { rank = split - k; break; }
            // far bins = low rank; within bin, last row-major source wins.
            // rank<0 (d==max or sentinel): dummy p=0 keeps segments dense.
            u32 p = (rank >= 0) ? (u32)rank * (u32)NPIX + (u32)(i + j) + 1u : 0u;
            int ty = t / WW, tx = t - ty * WW;
            int tile = (ty >> 6) * TCX + (tx >> 6);
            u32 pos = atomicAdd(&cur[tile], 1u);      // LDS only
            pairs[pos] = make_uint2((u32)t, p);
        }
    }
}

// ---- per-tile LDS z-buffer reduce + output write ----
__global__ __launch_bounds__(256) void k_tile_reduce(const uint2* __restrict__ pairs,
                                                     const u32* __restrict__ tbase,
                                                     const u32* __restrict__ tend,
                                                     const float* __restrict__ img,
                                                     float* __restrict__ out) {
    __shared__ u32 zb[TS * TS];
    int tid = threadIdx.x;
    int tile = blockIdx.x;
    for (int c = tid; c < TS * TS; c += 256) zb[c] = 0;
    __syncthreads();
    int ty0 = (tile / TCX) << 6, tx0 = (tile % TCX) << 6;
    u32 b = tbase[tile], e = tend[tile];
    for (u32 k = b + tid; k < e; k += 256) {
        uint2 pr = pairs[k];
        int t = (int)pr.x;
        int ty = t / WW, tx = t - ty * WW;
        atomicMax(&zb[((ty - ty0) << 6) | (tx - tx0)], pr.y);   // LDS
    }
    __syncthreads();
    for (int c = tid; c < TS * TS; c += 256) {
        int ty = ty0 + (c >> 6);
        if (ty >= HH) continue;
        int tx = tx0 + (c & 63);
        u32 p = zb[c];
        float r = 0.f, g = 0.f, bl = 0.f;
        if (p) {
            u32 src = (p - 1u) % (u32)NPIX;   // p-1 = rank*NPIX + src
            r  = img[src * 3 + 0];
            g  = img[src * 3 + 1];
            bl = img[src * 3 + 2];
        }
        int t = ty * WW + tx;
        out[t * 3 + 0] = r;
        out[t * 3 + 1] = g;
        out[t * 3 + 2] = bl;
    }
}

extern "C" void kernel_launch(void* const* d_in, const int* in_sizes, int n_in,
                              void* d_out, int out_size, void* d_ws, size_t ws_size,
                              hipStream_t stream) {
    const float* img    = (const float*)d_in[0];
    const float* flow   = (const float*)d_in[1];   // [1,H,W,2] flat == [H,W,2]
    const float* depth  = (const float*)d_in[2];
    const int*   splitp = (const int*)d_in[3];

    char* ws = (char*)d_ws;
    float* mids  = (float*)(ws + MIDS_OFF);
    u32*   qb1   = (u32*)(ws + QB1_OFF);
    u32*   qr1   = (u32*)(ws + QR1_OFF);
    u32*   oidx  = (u32*)(ws + OIDX_OFF);
    u32*   obin  = (u32*)(ws + OBIN_OFF);
    u32*   nown  = (u32*)(ws + NOWN_OFF);
    u32*   key22 = (u32*)(ws + KEY22_OFF);
    u32*   r2o   = (u32*)(ws + R2O_OFF);
    u32*   tot1  = (u32*)(ws + TOT1_OFF);
    u32*   gh2   = (u32*)(ws + GH2_OFF);
    u32*   tcnt  = (u32*)(ws + TCNT_OFF);
    u32*   ttot  = (u32*)(ws + TTOT_OFF);
    u32*   tbase = (u32*)(ws + TBASE_OFF);
    u32*   tend  = (u32*)(ws + TEND_OFF);
    u32*   base2 = (u32*)(ws + BASE2_OFF);
    u32*   gh1   = (u32*)(ws + GH1_OFF);
    uint2* pairs = (uint2*)(ws + PAIRS_OFF);
    float* out   = (float*)d_out;

    // zero: header + tot1 + gh2 only (~333 KB)
    hipMemsetAsync(d_ws, 0, ZERO_BYTES, stream);

    k_histA_cnt  <<<NBLK, 256, 0, stream>>>(depth, flow, tot1, tcnt);
    k_tsum       <<<NT512, 256, 0, stream>>>(tcnt, ttot);
    k_selA       <<<1, 1024, 0, stream>>>(tot1, splitp, ttot, qb1, qr1, oidx, obin, nown, tbase, tend);
    k_tscan      <<<NT512, 256, 0, stream>>>(tcnt, tbase, base2);
    k_ph1        <<<NCH1, 1024, 0, stream>>>(depth, obin, nown, gh1);
    k_red1       <<<NQ, 1024, 0, stream>>>(splitp, qb1, qr1, oidx, gh1, key22, r2o);
    k_ph2        <<<NBLK, 256, 0, stream>>>(depth, splitp, key22, gh2);
    k_red2       <<<NQ, 1024, 0, stream>>>(splitp, key22, r2o, gh2, mids);
    k_scatter    <<<NBLK, 256, 0, stream>>>(depth, flow, splitp, mids, base2, pairs);
    k_tile_reduce<<<NTILE, 256, 0, stream>>>(pairs, tbase, tend, img, out);
}

// Round 8
// 166.176 us; speedup vs baseline: 1.2333x; 1.2333x over previous
//
#include <hip/hip_runtime.h>

typedef unsigned int u32;

static constexpr int HH = 1080, WW = 1920;
static constexpr int NPIX = HH * WW;            // 2,073,600
static constexpr int NQ = 17;                   // supports split <= 16 (actual 10)
static constexpr int MAXOWN = 16;               // max distinct quantile hi-12 bins
static constexpr int OPB = 4;                   // owners per ph1 block (16 KB LDS)
static constexpr int NGRP = MAXOWN / OPB;       // 4 owner groups
static constexpr int NBLK = 256;                // grid for histA / ph2 / scatter (must match!)
static constexpr int R1 = 16;                   // replicas for level-1 bin merge
static constexpr int NCH1 = 64;                 // chunks for ph1
static constexpr int TS = 64;                   // target tile size
static constexpr int TCX = WW / TS;             // 30
static constexpr int TCY = (HH + TS - 1) / TS;  // 17
static constexpr int NTILE = TCX * TCY;         // 510 (padded to 512)
static constexpr int NT512 = 512;

// ---- workspace layout (bytes) ----
static constexpr size_t MIDS_OFF  = 0;     // float[32]
static constexpr size_t QB1_OFF   = 128;   // u32[32]
static constexpr size_t QR1_OFF   = 256;   // u32[32]
static constexpr size_t OIDX_OFF  = 384;   // u32[32]  query -> owner index
static constexpr size_t OBIN_OFF  = 512;   // u32[32]  owner -> hi-12 bin
static constexpr size_t NOWN_OFF  = 640;   // u32[1]
static constexpr size_t KEY22_OFF = 768;   // u32[32]  query -> 22-bit prefix
static constexpr size_t R2O_OFF   = 896;   // u32[32]  rank within 22-bit bin
static constexpr size_t TOT1_OFF  = 1024;                                   // u32[R1*4096]
static constexpr size_t GH2_OFF   = TOT1_OFF + (size_t)R1 * 4096 * 4;       // u32[NQ*1024]
static constexpr size_t ZERO_BYTES = GH2_OFF + (size_t)NQ * 1024 * 4;       // ~333 KB
static constexpr size_t TCNT_OFF  = ZERO_BYTES;                             // u32[NBLK*512] fully written
static constexpr size_t TTOT_OFF  = TCNT_OFF + (size_t)NBLK * NT512 * 4;    // u32[512]
static constexpr size_t TBASE_OFF = TTOT_OFF + NT512 * 4;                   // u32[512]
static constexpr size_t TEND_OFF  = TBASE_OFF + NT512 * 4;                  // u32[512]
static constexpr size_t BASE2_OFF = TEND_OFF + NT512 * 4;                   // u32[512*NBLK] (relative)
static constexpr size_t GH1_OFF   = BASE2_OFF + (size_t)NT512 * NBLK * 4;   // u32[MAXOWN*NCH1*1024]
static constexpr size_t PAIRS_OFF = GH1_OFF + (size_t)MAXOWN * NCH1 * 1024 * 4; // uint2[NPIX]

// ---- geometry helper: target pixel index, or -1 if dropped (flow-only) ----
__device__ __forceinline__ int target_of(int y, int x, float fx, float fy) {
    int ty = (int)rintf((float)y + fy);  // rintf = round-half-even = jnp.round
    int tx = (int)rintf((float)x + fx);
    if (ty < 0) ty += HH;                // JAX normalizes negative indices once
    if (tx < 0) tx += WW;
    if ((unsigned)ty >= (unsigned)HH || (unsigned)tx >= (unsigned)WW) return -1;
    return ty * WW + tx;
}

// ---- level 1: LDS 4096-bin histogram of bits[31:20] + per-(block,tile) target counts ----
__global__ __launch_bounds__(256) void k_histA_cnt(const float* __restrict__ depth,
                                                   const float* __restrict__ flow,
                                                   u32* __restrict__ tot1,
                                                   u32* __restrict__ tcnt) {
    __shared__ u32 h[4096];
    __shared__ u32 tc[NT512];
    for (int j = threadIdx.x; j < 4096; j += 256) h[j] = 0;
    for (int j = threadIdx.x; j < NT512; j += 256) tc[j] = 0;
    __syncthreads();
    const int nvec = NPIX / 4;
    for (int v = blockIdx.x * 256 + threadIdx.x; v < nvec; v += gridDim.x * 256) {
        int i = v * 4;
        float4 d4 = ((const float4*)depth)[v];
        float4 fa = ((const float4*)flow)[v * 2];
        float4 fb = ((const float4*)flow)[v * 2 + 1];
        int y = i / WW, x0 = i - y * WW;   // 4-group never crosses a row (WW%4==0)
        float dd[4] = {d4.x, d4.y, d4.z, d4.w};
        float fx[4] = {fa.x, fa.z, fb.x, fb.z};
        float fy[4] = {fa.y, fa.w, fb.y, fb.w};
        #pragma unroll
        for (int j = 0; j < 4; ++j) {
            if (dd[j] != 100.0f)                                   // sentinel excluded
                atomicAdd(&h[__float_as_uint(dd[j]) >> 20], 1u);   // d>0 -> monotonic bits
            int t = target_of(y, x0 + j, fx[j], fy[j]);
            if (t >= 0) {
                int ty = t / WW, tx = t - ty * WW;
                atomicAdd(&tc[(ty >> 6) * TCX + (tx >> 6)], 1u);
            }
        }
    }
    __syncthreads();
    u32 rep = blockIdx.x & (R1 - 1);
    for (int j = threadIdx.x; j < 4096; j += 256) {
        u32 v = h[j];
        if (v) atomicAdd(&tot1[rep * 4096 + j], v);   // short chains (<=16/address)
    }
    for (int j = threadIdx.x; j < NT512; j += 256)
        tcnt[blockIdx.x * NT512 + j] = tc[j];         // non-atomic per-block counts
}

// ---- per-(tile, block) relative write bases + per-tile totals ----
__global__ __launch_bounds__(256) void k_tscan(const u32* __restrict__ tcnt,
                                               u32* __restrict__ ttot,
                                               u32* __restrict__ base2) {
    __shared__ u32 s[256];
    int t = blockIdx.x, b = threadIdx.x;
    u32 v = tcnt[b * NT512 + t];
    s[b] = v;
    __syncthreads();
    for (int off = 1; off < 256; off <<= 1) {
        u32 x = (b >= off) ? s[b - off] : 0;
        __syncthreads();
        s[b] += x;
        __syncthreads();
    }
    base2[t * NBLK + b] = s[b] - v;   // relative exclusive prefix
    if (b == 255) ttot[t] = s[255];   // tile total
}

// ---- level-1 select + owner table + tile-total prefix sum ----
__global__ __launch_bounds__(1024) void k_selA(const u32* __restrict__ tot1,
                                               const int* __restrict__ splitp,
                                               const u32* __restrict__ ttot,
                                               u32* __restrict__ qb1, u32* __restrict__ qr1,
                                               u32* __restrict__ oidx, u32* __restrict__ obin,
                                               u32* __restrict__ nown,
                                               u32* __restrict__ tbase, u32* __restrict__ tend) {
    __shared__ u32 part[1024];
    __shared__ u32 qbS[NQ], qcS[NQ];
    __shared__ u32 totalsh;
    int tid = threadIdx.x;
    int split = *splitp;
    int base = tid * 4;
    u32 cc[4] = {0, 0, 0, 0};
    for (int r = 0; r < R1; ++r)
        for (int j = 0; j < 4; ++j) cc[j] += tot1[r * 4096 + base + j];
    u32 local = cc[0] + cc[1] + cc[2] + cc[3];
    part[tid] = local;
    __syncthreads();
    for (int off = 1; off < 1024; off <<= 1) {
        u32 v = (tid >= off) ? part[tid - off] : 0;
        __syncthreads();
        part[tid] += v;
        __syncthreads();
    }
    if (tid == 1023) totalsh = part[1023];
    __syncthreads();
    u32 l = totalsh;                 // valid-pixel count = histogram sum
    u32 step = l / (u32)split;
    u32 cum = part[tid] - local;     // exclusive prefix of this thread's 4 bins
    for (int j = 0; j < 4; ++j) {
        u32 c = cc[j];
        if (c) {
            for (int q = 0; q <= split; ++q) {
                u32 r = (q < split) ? (u32)q * step : l - 1u;
                if (r >= cum && r < cum + c) {
                    qb1[q] = (u32)(base + j);
                    qr1[q] = r - cum;
                    qbS[q] = (u32)(base + j);
                    qcS[q] = c;
                }
            }
        }
        cum += c;
    }
    __syncthreads();
    if (tid == 0) {   // owners: distinct (adjacent, ascending) hi-12 bins
        int w = -1;
        u32 prev = 0xFFFFFFFFu;
        for (int q = 0; q <= split; ++q) {
            if (qbS[q] != prev) { ++w; prev = qbS[q]; obin[w] = qbS[q]; }
            oidx[q] = (u32)w;
        }
        for (int w2 = w + 1; w2 < MAXOWN; ++w2) obin[w2] = 0xFFFFFFFFu;
        *nown = (u32)(w + 1);
    }
    __syncthreads();
    // ---- tile totals prefix sum -> tbase/tend ----
    u32 tv = (tid < NT512) ? ttot[tid] : 0;
    part[tid] = tv;
    __syncthreads();
    for (int off = 1; off < 1024; off <<= 1) {
        u32 v = (tid >= off) ? part[tid - off] : 0;
        __syncthreads();
        part[tid] += v;
        __syncthreads();
    }
    if (tid < NT512) {
        tbase[tid] = part[tid] - tv;
        tend[tid]  = part[tid];
    }
}

// ---- level 2: per-owner LDS hist of bits[19:10]; one block = (chunk, 4-owner group) ----
__global__ __launch_bounds__(256) void k_ph1(const float* __restrict__ depth,
                                             const u32* __restrict__ obin,
                                             const u32* __restrict__ nownp,
                                             u32* __restrict__ ghist) {
    int c = blockIdx.x / NGRP;          // chunk
    int g = blockIdx.x % NGRP;          // owner group
    int w0 = g * OPB;
    int nown = (int)*nownp;
    if (w0 >= nown) return;
    __shared__ u32 h[OPB * 1024];       // 16 KB
    int tid = threadIdx.x;
    u32 ob[OPB];
    #pragma unroll
    for (int k = 0; k < OPB; ++k)
        ob[k] = (w0 + k < nown) ? obin[w0 + k] : 0xFFFFFFFFu;   // sentinel never matches
    for (int j = tid; j < OPB * 1024; j += 256) h[j] = 0;
    __syncthreads();
    const int per = (NPIX / 4) / NCH1;  // 8100 float4 per chunk, exact
    int lo = c * per, hi = lo + per;
    for (int v = lo + tid; v < hi; v += 256) {
        float4 d4 = ((const float4*)depth)[v];
        float dd[4] = {d4.x, d4.y, d4.z, d4.w};
        #pragma unroll
        for (int j = 0; j < 4; ++j) {
            u32 bits = __float_as_uint(dd[j]);
            u32 b1 = bits >> 20;
            #pragma unroll
            for (int k = 0; k < OPB; ++k)
                if (ob[k] == b1)
                    atomicAdd(&h[k * 1024 + ((bits >> 10) & 1023u)], 1u);
        }
    }
    __syncthreads();
    for (int j = tid; j < OPB * 1024; j += 256) {
        int k = j >> 10, bin = j & 1023;
        int w = w0 + k;
        if (w < nown) ghist[(w * NCH1 + c) * 1024 + bin] = h[j];   // non-atomic chunk write
    }
}

// ---- level-2 reduce: chunks -> (key22, r2) per query ----
__global__ __launch_bounds__(1024) void k_red1(const int* __restrict__ splitp,
                                               const u32* __restrict__ qb1,
                                               const u32* __restrict__ qr1,
                                               const u32* __restrict__ oidx,
                                               const u32* __restrict__ ghist,
                                               u32* __restrict__ key22, u32* __restrict__ r2o) {
    int q = blockIdx.x;
    if (q > *splitp) return;
    int w = (int)oidx[q];
    __shared__ u32 part[1024];
    int tid = threadIdx.x;
    u32 local = 0;
    for (int c = 0; c < NCH1; ++c) local += ghist[(w * NCH1 + c) * 1024 + tid];
    part[tid] = local;
    __syncthreads();
    for (int off = 1; off < 1024; off <<= 1) {
        u32 v = (tid >= off) ? part[tid - off] : 0;
        __syncthreads();
        part[tid] += v;
        __syncthreads();
    }
    u32 target = qr1[q];
    u32 cum = part[tid] - local;
    if (local && target >= cum && target < cum + local) {
        key22[q] = (qb1[q] << 10) | (u32)tid;
        r2o[q] = target - cum;
    }
}

// ---- level 3: low-10-bit histogram restricted to 22-bit keys (tiny atomic count) ----
__global__ __launch_bounds__(256) void k_ph2(const float* __restrict__ depth,
                                             const int* __restrict__ splitp,
                                             const u32* __restrict__ key22,
                                             u32* __restrict__ gh2) {
    __shared__ u32 k22[NQ];
    int tid = threadIdx.x, split = *splitp;
    if (tid < NQ) k22[tid] = (tid <= split) ? key22[tid] : 0xFFFFFFFFu;
    __syncthreads();
    const int nvec = NPIX / 4;
    for (int v = blockIdx.x * 256 + tid; v < nvec; v += gridDim.x * 256) {
        float4 d4 = ((const float4*)depth)[v];
        float dd[4] = {d4.x, d4.y, d4.z, d4.w};
        #pragma unroll
        for (int j = 0; j < 4; ++j) {
            if (dd[j] != 100.0f) {
                u32 bits = __float_as_uint(dd[j]);
                u32 hi22 = bits >> 10;
                for (int q = 0; q <= split; ++q)
                    if (k22[q] == hi22) atomicAdd(&gh2[q * 1024 + (bits & 1023u)], 1u);
            }
        }
    }
}

// ---- level-3 reduce: exact order-statistic floats ----
__global__ __launch_bounds__(1024) void k_red2(const int* __restrict__ splitp,
                                               const u32* __restrict__ key22,
                                               const u32* __restrict__ r2o,
                                               const u32* __restrict__ gh2,
                                               float* __restrict__ mids) {
    int q = blockIdx.x;
    if (q > *splitp) return;
    __shared__ u32 part[1024];
    int tid = threadIdx.x;
    u32 local = gh2[q * 1024 + tid];
    part[tid] = local;
    __syncthreads();
    for (int off = 1; off < 1024; off <<= 1) {
        u32 v = (tid >= off) ? part[tid - off] : 0;
        __syncthreads();
        part[tid] += v;
        __syncthreads();
    }
    u32 target = r2o[q];
    u32 cum = part[tid] - local;
    if (local && target >= cum && target < cum + local)
        mids[q] = __uint_as_float((key22[q] << 10) | (u32)tid);
}

// ---- scatter: exact-base pair writes, zero device atomics, no inner barriers ----
__global__ __launch_bounds__(256) void k_scatter(const float* __restrict__ depth,
                                                 const float* __restrict__ flow,
                                                 const int* __restrict__ splitp,
                                                 const float* __restrict__ mids,
                                                 const u32* __restrict__ tbase,
                                                 const u32* __restrict__ base2,
                                                 uint2* __restrict__ pairs) {
    __shared__ u32 cur[NT512];
    __shared__ float msh[NQ];
    int tid = threadIdx.x, split = *splitp;
    if (tid < NQ) msh[tid] = (tid <= split) ? mids[tid] : 0.f;
    for (int j = tid; j < NT512; j += 256)
        cur[j] = tbase[j] + base2[j * NBLK + blockIdx.x];
    __syncthreads();
    const int nvec = NPIX / 4;   // traversal MUST match k_histA_cnt exactly
    for (int v = blockIdx.x * 256 + tid; v < nvec; v += gridDim.x * 256) {
        int i = v * 4;
        float4 d4 = ((const float4*)depth)[v];
        float4 fa = ((const float4*)flow)[v * 2];
        float4 fb = ((const float4*)flow)[v * 2 + 1];
        int y = i / WW, x0 = i - y * WW;
        float dd[4] = {d4.x, d4.y, d4.z, d4.w};
        float fx[4] = {fa.x, fa.z, fb.x, fb.z};
        float fy[4] = {fa.y, fa.w, fb.y, fb.w};
        #pragma unroll
        for (int j = 0; j < 4; ++j) {
            int t = target_of(y, x0 + j, fx[j], fy[j]);
            if (t < 0) continue;                      // only this drop counted by histA too
            float d = dd[j];
            int rank = -1;
            for (int k = 1; k <= split; ++k)
                if (d >= msh[k - 1] && d < msh[k]) { rank = split - k; break; }
            // far bins = low rank; within bin, last row-major source wins.
            // rank<0 (d==max or sentinel): dummy p=0 keeps segments dense.
            u32 p = (rank >= 0) ? (u32)rank * (u32)NPIX + (u32)(i + j) + 1u : 0u;
            int ty = t / WW, tx = t - ty * WW;
            int tile = (ty >> 6) * TCX + (tx >> 6);
            u32 pos = atomicAdd(&cur[tile], 1u);      // LDS only
            pairs[pos] = make_uint2((u32)t, p);
        }
    }
}

// ---- per-tile LDS z-buffer reduce + output write ----
__global__ __launch_bounds__(256) void k_tile_reduce(const uint2* __restrict__ pairs,
                                                     const u32* __restrict__ tbase,
                                                     const u32* __restrict__ tend,
                                                     const float* __restrict__ img,
                                                     float* __restrict__ out) {
    __shared__ u32 zb[TS * TS];
    int tid = threadIdx.x;
    int tile = blockIdx.x;
    for (int c = tid; c < TS * TS; c += 256) zb[c] = 0;
    __syncthreads();
    int ty0 = (tile / TCX) << 6, tx0 = (tile % TCX) << 6;
    u32 b = tbase[tile], e = tend[tile];
    for (u32 k = b + tid; k < e; k += 256) {
        uint2 pr = pairs[k];
        int t = (int)pr.x;
        int ty = t / WW, tx = t - ty * WW;
        atomicMax(&zb[((ty - ty0) << 6) | (tx - tx0)], pr.y);   // LDS
    }
    __syncthreads();
    for (int c = tid; c < TS * TS; c += 256) {
        int ty = ty0 + (c >> 6);
        if (ty >= HH) continue;
        int tx = tx0 + (c & 63);
        u32 p = zb[c];
        float r = 0.f, g = 0.f, bl = 0.f;
        if (p) {
            u32 src = (p - 1u) % (u32)NPIX;   // p-1 = rank*NPIX + src
            r  = img[src * 3 + 0];
            g  = img[src * 3 + 1];
            bl = img[src * 3 + 2];
        }
        int t = ty * WW + tx;
        out[t * 3 + 0] = r;
        out[t * 3 + 1] = g;
        out[t * 3 + 2] = bl;
    }
}

extern "C" void kernel_launch(void* const* d_in, const int* in_sizes, int n_in,
                              void* d_out, int out_size, void* d_ws, size_t ws_size,
                              hipStream_t stream) {
    const float* img    = (const float*)d_in[0];
    const float* flow   = (const float*)d_in[1];   // [1,H,W,2] flat == [H,W,2]
    const float* depth  = (const float*)d_in[2];
    const int*   splitp = (const int*)d_in[3];

    char* ws = (char*)d_ws;
    float* mids  = (float*)(ws + MIDS_OFF);
    u32*   qb1   = (u32*)(ws + QB1_OFF);
    u32*   qr1   = (u32*)(ws + QR1_OFF);
    u32*   oidx  = (u32*)(ws + OIDX_OFF);
    u32*   obin  = (u32*)(ws + OBIN_OFF);
    u32*   nown  = (u32*)(ws + NOWN_OFF);
    u32*   key22 = (u32*)(ws + KEY22_OFF);
    u32*   r2o   = (u32*)(ws + R2O_OFF);
    u32*   tot1  = (u32*)(ws + TOT1_OFF);
    u32*   gh2   = (u32*)(ws + GH2_OFF);
    u32*   tcnt  = (u32*)(ws + TCNT_OFF);
    u32*   ttot  = (u32*)(ws + TTOT_OFF);
    u32*   tbase = (u32*)(ws + TBASE_OFF);
    u32*   tend  = (u32*)(ws + TEND_OFF);
    u32*   base2 = (u32*)(ws + BASE2_OFF);
    u32*   gh1   = (u32*)(ws + GH1_OFF);
    uint2* pairs = (uint2*)(ws + PAIRS_OFF);
    float* out   = (float*)d_out;

    // zero: header + tot1 + gh2 only (~333 KB)
    hipMemsetAsync(d_ws, 0, ZERO_BYTES, stream);

    k_histA_cnt  <<<NBLK, 256, 0, stream>>>(depth, flow, tot1, tcnt);
    k_tscan      <<<NT512, 256, 0, stream>>>(tcnt, ttot, base2);
    k_selA       <<<1, 1024, 0, stream>>>(tot1, splitp, ttot, qb1, qr1, oidx, obin, nown, tbase, tend);
    k_ph1        <<<NCH1 * NGRP, 256, 0, stream>>>(depth, obin, nown, gh1);
    k_red1       <<<NQ, 1024, 0, stream>>>(splitp, qb1, qr1, oidx, gh1, key22, r2o);
    k_ph2        <<<NBLK, 256, 0, stream>>>(depth, splitp, key22, gh2);
    k_red2       <<<NQ, 1024, 0, stream>>>(splitp, key22, r2o, gh2, mids);
    k_scatter    <<<NBLK, 256, 0, stream>>>(depth, flow, splitp, mids, tbase, base2, pairs);
    k_tile_reduce<<<NTILE, 256, 0, stream>>>(pairs, tbase, tend, img, out);
}

// Round 9
// 96.923 us; speedup vs baseline: 2.1146x; 1.7145x over previous
//
#include <hip/hip_runtime.h>

typedef unsigned int u32;

static constexpr int HH = 1080, WW = 1920;
static constexpr int NPIX = HH * WW;            // 2,073,600
static constexpr int NQ = 17;                   // supports split <= 16 (actual 10)
static constexpr int MAXOWN = 16;               // max distinct quantile hi-12 bins
static constexpr int OPB = 4;                   // owners per ph1 block (16 KB LDS)
static constexpr int NGRP = MAXOWN / OPB;       // 4 owner groups
static constexpr int NBLK = 512;                // grid for histA / scatter (must match!)
static constexpr int BT   = 1024;               // their block size
static constexpr int R1 = 16;                   // replicas for level-1 bin merge
static constexpr int NCH1 = 64;                 // chunks for ph1
static constexpr int TS = 64;                   // target tile size
static constexpr int TCX = WW / TS;             // 30
static constexpr int TCY = (HH + TS - 1) / TS;  // 17
static constexpr int NTILE = TCX * TCY;         // 510 (padded to 512)
static constexpr int NT512 = 512;

// ---- workspace layout (bytes) ----
static constexpr size_t MIDS_OFF  = 0;     // float[32]
static constexpr size_t QB1_OFF   = 128;   // u32[32]
static constexpr size_t QR1_OFF   = 256;   // u32[32]
static constexpr size_t OIDX_OFF  = 384;   // u32[32]  query -> owner index
static constexpr size_t OBIN_OFF  = 512;   // u32[32]  owner -> hi-12 bin
static constexpr size_t NOWN_OFF  = 640;   // u32[1]
static constexpr size_t KEY22_OFF = 768;   // u32[32]  query -> 22-bit prefix
static constexpr size_t R2O_OFF   = 896;   // u32[32]  rank within 22-bit bin
static constexpr size_t TOT1_OFF  = 1024;                                   // u32[R1*4096]
static constexpr size_t GH2_OFF   = TOT1_OFF + (size_t)R1 * 4096 * 4;       // u32[NQ*1024]
static constexpr size_t ZERO_BYTES = GH2_OFF + (size_t)NQ * 1024 * 4;       // ~333 KB
static constexpr size_t TCNT_OFF  = ZERO_BYTES;                             // u32[NBLK*512] fully written
static constexpr size_t TTOT_OFF  = TCNT_OFF + (size_t)NBLK * NT512 * 4;    // u32[512]
static constexpr size_t TBASE_OFF = TTOT_OFF + NT512 * 4;                   // u32[512]
static constexpr size_t TEND_OFF  = TBASE_OFF + NT512 * 4;                  // u32[512]
static constexpr size_t BASE2_OFF = TEND_OFF + NT512 * 4;                   // u32[NBLK*512] ([blk][tile], relative)
static constexpr size_t GH1_OFF   = BASE2_OFF + (size_t)NBLK * NT512 * 4;   // u32[MAXOWN*NCH1*1024]
static constexpr size_t PAIRS_OFF = GH1_OFF + (size_t)MAXOWN * NCH1 * 1024 * 4; // uint2[NPIX]

// ---- geometry helper: target pixel index, or -1 if dropped (flow-only) ----
__device__ __forceinline__ int target_of(int y, int x, float fx, float fy) {
    int ty = (int)rintf((float)y + fy);  // rintf = round-half-even = jnp.round
    int tx = (int)rintf((float)x + fx);
    if (ty < 0) ty += HH;                // JAX normalizes negative indices once
    if (tx < 0) tx += WW;
    if ((unsigned)ty >= (unsigned)HH || (unsigned)tx >= (unsigned)WW) return -1;
    return ty * WW + tx;
}

// ---- level 1: LDS 4096-bin histogram of bits[31:20] + per-(block,tile) target counts ----
__global__ __launch_bounds__(BT) void k_histA_cnt(const float* __restrict__ depth,
                                                  const float* __restrict__ flow,
                                                  u32* __restrict__ tot1,
                                                  u32* __restrict__ tcnt) {
    __shared__ u32 h[4096];
    __shared__ u32 tc[NT512];
    int tid = threadIdx.x;
    for (int j = tid; j < 4096; j += BT) h[j] = 0;
    for (int j = tid; j < NT512; j += BT) tc[j] = 0;
    __syncthreads();
    const int nvec = NPIX / 4;
    for (int v = blockIdx.x * BT + tid; v < nvec; v += gridDim.x * BT) {
        int i = v * 4;
        float4 d4 = ((const float4*)depth)[v];
        float4 fa = ((const float4*)flow)[v * 2];
        float4 fb = ((const float4*)flow)[v * 2 + 1];
        int y = i / WW, x0 = i - y * WW;   // 4-group never crosses a row (WW%4==0)
        float dd[4] = {d4.x, d4.y, d4.z, d4.w};
        float fx[4] = {fa.x, fa.z, fb.x, fb.z};
        float fy[4] = {fa.y, fa.w, fb.y, fb.w};
        #pragma unroll
        for (int j = 0; j < 4; ++j) {
            if (dd[j] != 100.0f)                                   // sentinel excluded
                atomicAdd(&h[__float_as_uint(dd[j]) >> 20], 1u);   // d>0 -> monotonic bits
            int t = target_of(y, x0 + j, fx[j], fy[j]);
            if (t >= 0) {
                int ty = t / WW, tx = t - ty * WW;
                atomicAdd(&tc[(ty >> 6) * TCX + (tx >> 6)], 1u);
            }
        }
    }
    __syncthreads();
    u32 rep = blockIdx.x & (R1 - 1);
    for (int j = tid; j < 4096; j += BT) {
        u32 v = h[j];
        if (v) atomicAdd(&tot1[rep * 4096 + j], v);   // sparse, short chains
    }
    for (int j = tid; j < NT512; j += BT)
        tcnt[blockIdx.x * NT512 + j] = tc[j];         // non-atomic per-block counts
}

// ---- per-(tile, block) relative write bases (transposed) + per-tile totals ----
__global__ __launch_bounds__(NBLK) void k_tscan(const u32* __restrict__ tcnt,
                                                u32* __restrict__ ttot,
                                                u32* __restrict__ base2) {
    __shared__ u32 s[NBLK];
    int t = blockIdx.x, b = threadIdx.x;
    u32 v = tcnt[b * NT512 + t];
    s[b] = v;
    __syncthreads();
    for (int off = 1; off < NBLK; off <<= 1) {
        u32 x = (b >= off) ? s[b - off] : 0;
        __syncthreads();
        s[b] += x;
        __syncthreads();
    }
    base2[b * NT512 + t] = s[b] - v;     // [blk][tile]: coalesced read in scatter
    if (b == NBLK - 1) ttot[t] = s[NBLK - 1];
}

// ---- level-1 select + owner table + tile-total prefix sum ----
__global__ __launch_bounds__(1024) void k_selA(const u32* __restrict__ tot1,
                                               const int* __restrict__ splitp,
                                               const u32* __restrict__ ttot,
                                               u32* __restrict__ qb1, u32* __restrict__ qr1,
                                               u32* __restrict__ oidx, u32* __restrict__ obin,
                                               u32* __restrict__ nown,
                                               u32* __restrict__ tbase, u32* __restrict__ tend) {
    __shared__ u32 part[1024];
    __shared__ u32 qbS[NQ], qcS[NQ];
    __shared__ u32 totalsh;
    int tid = threadIdx.x;
    int split = *splitp;
    int base = tid * 4;
    u32 cc[4] = {0, 0, 0, 0};
    for (int r = 0; r < R1; ++r)
        for (int j = 0; j < 4; ++j) cc[j] += tot1[r * 4096 + base + j];
    u32 local = cc[0] + cc[1] + cc[2] + cc[3];
    part[tid] = local;
    __syncthreads();
    for (int off = 1; off < 1024; off <<= 1) {
        u32 v = (tid >= off) ? part[tid - off] : 0;
        __syncthreads();
        part[tid] += v;
        __syncthreads();
    }
    if (tid == 1023) totalsh = part[1023];
    __syncthreads();
    u32 l = totalsh;                 // valid-pixel count = histogram sum
    u32 step = l / (u32)split;
    u32 cum = part[tid] - local;     // exclusive prefix of this thread's 4 bins
    for (int j = 0; j < 4; ++j) {
        u32 c = cc[j];
        if (c) {
            for (int q = 0; q <= split; ++q) {
                u32 r = (q < split) ? (u32)q * step : l - 1u;
                if (r >= cum && r < cum + c) {
                    qb1[q] = (u32)(base + j);
                    qr1[q] = r - cum;
                    qbS[q] = (u32)(base + j);
                    qcS[q] = c;
                }
            }
        }
        cum += c;
    }
    __syncthreads();
    if (tid == 0) {   // owners: distinct (adjacent, ascending) hi-12 bins
        int w = -1;
        u32 prev = 0xFFFFFFFFu;
        for (int q = 0; q <= split; ++q) {
            if (qbS[q] != prev) { ++w; prev = qbS[q]; obin[w] = qbS[q]; }
            oidx[q] = (u32)w;
        }
        for (int w2 = w + 1; w2 < MAXOWN; ++w2) obin[w2] = 0xFFFFFFFFu;
        *nown = (u32)(w + 1);
    }
    __syncthreads();
    // ---- tile totals prefix sum -> tbase/tend ----
    u32 tv = (tid < NT512) ? ttot[tid] : 0;
    part[tid] = tv;
    __syncthreads();
    for (int off = 1; off < 1024; off <<= 1) {
        u32 v = (tid >= off) ? part[tid - off] : 0;
        __syncthreads();
        part[tid] += v;
        __syncthreads();
    }
    if (tid < NT512) {
        tbase[tid] = part[tid] - tv;
        tend[tid]  = part[tid];
    }
}

// ---- level 2: per-owner LDS hist of bits[19:10]; one block = (chunk, 4-owner group) ----
__global__ __launch_bounds__(1024) void k_ph1(const float* __restrict__ depth,
                                              const u32* __restrict__ obin,
                                              const u32* __restrict__ nownp,
                                              u32* __restrict__ ghist) {
    int c = blockIdx.x / NGRP;          // chunk
    int g = blockIdx.x % NGRP;          // owner group
    int w0 = g * OPB;
    int nown = (int)*nownp;
    if (w0 >= nown) return;
    __shared__ u32 h[OPB * 1024];       // 16 KB
    int tid = threadIdx.x;
    u32 ob[OPB];
    #pragma unroll
    for (int k = 0; k < OPB; ++k)
        ob[k] = (w0 + k < nown) ? obin[w0 + k] : 0xFFFFFFFFu;   // sentinel never matches
    for (int j = tid; j < OPB * 1024; j += 1024) h[j] = 0;
    __syncthreads();
    const int per = (NPIX / 4) / NCH1;  // 8100 float4 per chunk, exact
    int lo = c * per, hi = lo + per;
    for (int v = lo + tid; v < hi; v += 1024) {
        float4 d4 = ((const float4*)depth)[v];
        float dd[4] = {d4.x, d4.y, d4.z, d4.w};
        #pragma unroll
        for (int j = 0; j < 4; ++j) {
            u32 bits = __float_as_uint(dd[j]);
            u32 b1 = bits >> 20;
            #pragma unroll
            for (int k = 0; k < OPB; ++k)
                if (ob[k] == b1)
                    atomicAdd(&h[k * 1024 + ((bits >> 10) & 1023u)], 1u);
        }
    }
    __syncthreads();
    for (int j = tid; j < OPB * 1024; j += 1024) {
        int k = j >> 10, bin = j & 1023;
        int w = w0 + k;
        if (w < nown) ghist[(w * NCH1 + c) * 1024 + bin] = h[j];   // non-atomic chunk write
    }
}

// ---- level-2 reduce: chunks -> (key22, r2) per query ----
__global__ __launch_bounds__(1024) void k_red1(const int* __restrict__ splitp,
                                               const u32* __restrict__ qb1,
                                               const u32* __restrict__ qr1,
                                               const u32* __restrict__ oidx,
                                               const u32* __restrict__ ghist,
                                               u32* __restrict__ key22, u32* __restrict__ r2o) {
    int q = blockIdx.x;
    if (q > *splitp) return;
    int w = (int)oidx[q];
    __shared__ u32 part[1024];
    int tid = threadIdx.x;
    u32 local = 0;
    for (int c = 0; c < NCH1; ++c) local += ghist[(w * NCH1 + c) * 1024 + tid];
    part[tid] = local;
    __syncthreads();
    for (int off = 1; off < 1024; off <<= 1) {
        u32 v = (tid >= off) ? part[tid - off] : 0;
        __syncthreads();
        part[tid] += v;
        __syncthreads();
    }
    u32 target = qr1[q];
    u32 cum = part[tid] - local;
    if (local && target >= cum && target < cum + local) {
        key22[q] = (qb1[q] << 10) | (u32)tid;
        r2o[q] = target - cum;
    }
}

// ---- level 3: low-10-bit histogram restricted to 22-bit keys (tiny atomic count) ----
__global__ __launch_bounds__(256) void k_ph2(const float* __restrict__ depth,
                                             const int* __restrict__ splitp,
                                             const u32* __restrict__ key22,
                                             u32* __restrict__ gh2) {
    __shared__ u32 k22[NQ];
    int tid = threadIdx.x, split = *splitp;
    if (tid < NQ) k22[tid] = (tid <= split) ? key22[tid] : 0xFFFFFFFFu;
    __syncthreads();
    const int nvec = NPIX / 4;
    for (int v = blockIdx.x * blockDim.x + tid; v < nvec; v += gridDim.x * blockDim.x) {
        float4 d4 = ((const float4*)depth)[v];
        float dd[4] = {d4.x, d4.y, d4.z, d4.w};
        #pragma unroll
        for (int j = 0; j < 4; ++j) {
            if (dd[j] != 100.0f) {
                u32 bits = __float_as_uint(dd[j]);
                u32 hi22 = bits >> 10;
                for (int q = 0; q <= split; ++q)
                    if (k22[q] == hi22) atomicAdd(&gh2[q * 1024 + (bits & 1023u)], 1u);
            }
        }
    }
}

// ---- level-3 reduce: exact order-statistic floats ----
__global__ __launch_bounds__(1024) void k_red2(const int* __restrict__ splitp,
                                               const u32* __restrict__ key22,
                                               const u32* __restrict__ r2o,
                                               const u32* __restrict__ gh2,
                                               float* __restrict__ mids) {
    int q = blockIdx.x;
    if (q > *splitp) return;
    __shared__ u32 part[1024];
    int tid = threadIdx.x;
    u32 local = gh2[q * 1024 + tid];
    part[tid] = local;
    __syncthreads();
    for (int off = 1; off < 1024; off <<= 1) {
        u32 v = (tid >= off) ? part[tid - off] : 0;
        __syncthreads();
        part[tid] += v;
        __syncthreads();
    }
    u32 target = r2o[q];
    u32 cum = part[tid] - local;
    if (local && target >= cum && target < cum + local)
        mids[q] = __uint_as_float((key22[q] << 10) | (u32)tid);
}

// ---- scatter: exact-base pair writes, zero device atomics, no inner barriers ----
__global__ __launch_bounds__(BT) void k_scatter(const float* __restrict__ depth,
                                                const float* __restrict__ flow,
                                                const int* __restrict__ splitp,
                                                const float* __restrict__ mids,
                                                const u32* __restrict__ tbase,
                                                const u32* __restrict__ base2,
                                                uint2* __restrict__ pairs) {
    __shared__ u32 cur[NT512];
    __shared__ float msh[NQ];
    int tid = threadIdx.x, split = *splitp;
    if (tid < NQ) msh[tid] = (tid <= split) ? mids[tid] : 0.f;
    for (int j = tid; j < NT512; j += BT)
        cur[j] = tbase[j] + base2[blockIdx.x * NT512 + j];   // coalesced 2 KB read
    __syncthreads();
    const int nvec = NPIX / 4;   // traversal MUST match k_histA_cnt exactly
    for (int v = blockIdx.x * BT + tid; v < nvec; v += gridDim.x * BT) {
        int i = v * 4;
        float4 d4 = ((const float4*)depth)[v];
        float4 fa = ((const float4*)flow)[v * 2];
        float4 fb = ((const float4*)flow)[v * 2 + 1];
        int y = i / WW, x0 = i - y * WW;
        float dd[4] = {d4.x, d4.y, d4.z, d4.w};
        float fx[4] = {fa.x, fa.z, fb.x, fb.z};
        float fy[4] = {fa.y, fa.w, fb.y, fb.w};
        #pragma unroll
        for (int j = 0; j < 4; ++j) {
            int t = target_of(y, x0 + j, fx[j], fy[j]);
            if (t < 0) continue;                      // only this drop counted by histA too
            float d = dd[j];
            int rank = -1;
            for (int k = 1; k <= split; ++k)
                if (d >= msh[k - 1] && d < msh[k]) { rank = split - k; break; }
            // far bins = low rank; within bin, last row-major source wins.
            // rank<0 (d==max or sentinel): dummy p=0 keeps segments dense.
            u32 p = (rank >= 0) ? (u32)rank * (u32)NPIX + (u32)(i + j) + 1u : 0u;
            int ty = t / WW, tx = t - ty * WW;
            int tile = (ty >> 6) * TCX + (tx >> 6);
            u32 pos = atomicAdd(&cur[tile], 1u);      // LDS only
            pairs[pos] = make_uint2((u32)t, p);
        }
    }
}

// ---- per-tile LDS z-buffer reduce + output write ----
__global__ __launch_bounds__(1024) void k_tile_reduce(const uint2* __restrict__ pairs,
                                                      const u32* __restrict__ tbase,
                                                      const u32* __restrict__ tend,
                                                      const float* __restrict__ img,
                                                      float* __restrict__ out) {
    __shared__ u32 zb[TS * TS];
    int tid = threadIdx.x;
    int tile = blockIdx.x;
    for (int c = tid; c < TS * TS; c += 1024) zb[c] = 0;
    __syncthreads();
    int ty0 = (tile / TCX) << 6, tx0 = (tile % TCX) << 6;
    u32 b = tbase[tile], e = tend[tile];
    for (u32 k = b + tid; k < e; k += 1024) {
        uint2 pr = pairs[k];
        int t = (int)pr.x;
        int ty = t / WW, tx = t - ty * WW;
        atomicMax(&zb[((ty - ty0) << 6) | (tx - tx0)], pr.y);   // LDS
    }
    __syncthreads();
    for (int c = tid; c < TS * TS; c += 1024) {
        int ty = ty0 + (c >> 6);
        if (ty >= HH) continue;
        int tx = tx0 + (c & 63);
        u32 p = zb[c];
        float r = 0.f, g = 0.f, bl = 0.f;
        if (p) {
            u32 src = (p - 1u) % (u32)NPIX;   // p-1 = rank*NPIX + src
            r  = img[src * 3 + 0];
            g  = img[src * 3 + 1];
            bl = img[src * 3 + 2];
        }
        int t = ty * WW + tx;
        out[t * 3 + 0] = r;
        out[t * 3 + 1] = g;
        out[t * 3 + 2] = bl;
    }
}

extern "C" void kernel_launch(void* const* d_in, const int* in_sizes, int n_in,
                              void* d_out, int out_size, void* d_ws, size_t ws_size,
                              hipStream_t stream) {
    const float* img    = (const float*)d_in[0];
    const float* flow   = (const float*)d_in[1];   // [1,H,W,2] flat == [H,W,2]
    const float* depth  = (const float*)d_in[2];
    const int*   splitp = (const int*)d_in[3];

    char* ws = (char*)d_ws;
    float* mids  = (float*)(ws + MIDS_OFF);
    u32*   qb1   = (u32*)(ws + QB1_OFF);
    u32*   qr1   = (u32*)(ws + QR1_OFF);
    u32*   oidx  = (u32*)(ws + OIDX_OFF);
    u32*   obin  = (u32*)(ws + OBIN_OFF);
    u32*   nown  = (u32*)(ws + NOWN_OFF);
    u32*   key22 = (u32*)(ws + KEY22_OFF);
    u32*   r2o   = (u32*)(ws + R2O_OFF);
    u32*   tot1  = (u32*)(ws + TOT1_OFF);
    u32*   gh2   = (u32*)(ws + GH2_OFF);
    u32*   tcnt  = (u32*)(ws + TCNT_OFF);
    u32*   ttot  = (u32*)(ws + TTOT_OFF);
    u32*   tbase = (u32*)(ws + TBASE_OFF);
    u32*   tend  = (u32*)(ws + TEND_OFF);
    u32*   base2 = (u32*)(ws + BASE2_OFF);
    u32*   gh1   = (u32*)(ws + GH1_OFF);
    uint2* pairs = (uint2*)(ws + PAIRS_OFF);
    float* out   = (float*)d_out;

    // zero: header + tot1 + gh2 only (~333 KB)
    hipMemsetAsync(d_ws, 0, ZERO_BYTES, stream);

    k_histA_cnt  <<<NBLK, BT, 0, stream>>>(depth, flow, tot1, tcnt);
    k_tscan      <<<NT512, NBLK, 0, stream>>>(tcnt, ttot, base2);
    k_selA       <<<1, 1024, 0, stream>>>(tot1, splitp, ttot, qb1, qr1, oidx, obin, nown, tbase, tend);
    k_ph1        <<<NCH1 * NGRP, 1024, 0, stream>>>(depth, obin, nown, gh1);
    k_red1       <<<NQ, 1024, 0, stream>>>(splitp, qb1, qr1, oidx, gh1, key22, r2o);
    k_ph2        <<<2048, 256, 0, stream>>>(depth, splitp, key22, gh2);
    k_red2       <<<NQ, 1024, 0, stream>>>(splitp, key22, r2o, gh2, mids);
    k_scatter    <<<NBLK, BT, 0, stream>>>(depth, flow, splitp, mids, tbase, base2, pairs);
    k_tile_reduce<<<NTILE, 1024, 0, stream>>>(pairs, tbase, tend, img, out);
}

// Round 10
// 95.809 us; speedup vs baseline: 2.1391x; 1.0116x over previous
//
#include <hip/hip_runtime.h>

typedef unsigned int u32;

static constexpr int HH = 1080, WW = 1920;
static constexpr int NPIX = HH * WW;            // 2,073,600
static constexpr int NQ = 17;                   // supports split <= 16 (actual 10)
static constexpr int MAXOWN = 16;               // max distinct quantile hi-12 bins
static constexpr int OPB = 4;                   // owners per ph1 block (16 KB LDS)
static constexpr int NGRP = MAXOWN / OPB;       // 4 owner groups
static constexpr int NBLK = 512;                // grid for histA / scatter (must match!)
static constexpr int BT   = 1024;               // their block size
static constexpr int R1 = 16;                   // replicas for level-1 bin merge
static constexpr int NCH1 = 64;                 // chunks for ph1
static constexpr int TS = 64;                   // target tile size
static constexpr int TCX = WW / TS;             // 30
static constexpr int TCY = (HH + TS - 1) / TS;  // 17
static constexpr int NTILE = TCX * TCY;         // 510 (padded to 512)
static constexpr int NT512 = 512;

// ---- workspace layout (bytes) ----
static constexpr size_t MIDS_OFF  = 0;     // float[32]
static constexpr size_t QB1_OFF   = 128;   // u32[32]
static constexpr size_t QR1_OFF   = 256;   // u32[32]
static constexpr size_t OIDX_OFF  = 384;   // u32[32]  query -> owner index
static constexpr size_t OBIN_OFF  = 512;   // u32[32]  owner -> hi-12 bin
static constexpr size_t NOWN_OFF  = 640;   // u32[1]
static constexpr size_t KEY22_OFF = 768;   // u32[32]  query -> 22-bit prefix
static constexpr size_t R2O_OFF   = 896;   // u32[32]  rank within 22-bit bin
static constexpr size_t TOT1_OFF  = 1024;                                   // u32[R1*4096]
static constexpr size_t GH2_OFF   = TOT1_OFF + (size_t)R1 * 4096 * 4;       // u32[NQ*1024]
static constexpr size_t ZERO_BYTES = GH2_OFF + (size_t)NQ * 1024 * 4;       // 332,800 B (16-aligned)
static constexpr size_t TCNT_OFF  = ZERO_BYTES;                             // u32[NBLK*512] fully written
static constexpr size_t TTOT_OFF  = TCNT_OFF + (size_t)NBLK * NT512 * 4;    // u32[512]
static constexpr size_t TBASE_OFF = TTOT_OFF + NT512 * 4;                   // u32[512]
static constexpr size_t TEND_OFF  = TBASE_OFF + NT512 * 4;                  // u32[512]
static constexpr size_t BASE2_OFF = TEND_OFF + NT512 * 4;                   // u32[NBLK*512] ([blk][tile], relative)
static constexpr size_t GH1_OFF   = BASE2_OFF + (size_t)NBLK * NT512 * 4;   // u32[MAXOWN*NCH1*1024]
static constexpr size_t PAIRS_OFF = GH1_OFF + (size_t)MAXOWN * NCH1 * 1024 * 4; // uint2[NPIX]

static constexpr int ZVEC = (int)(ZERO_BYTES / 16);   // 20,800 float4
static constexpr int ZBLK = (ZVEC + 255) / 256;       // 82 blocks

// ---- zero the header+tot1+gh2 region (replaces pathological runtime small-fill) ----
__global__ __launch_bounds__(256) void k_zero(float4* __restrict__ ws) {
    int i = blockIdx.x * 256 + threadIdx.x;
    if (i < ZVEC) ws[i] = make_float4(0.f, 0.f, 0.f, 0.f);
}

// ---- geometry helper: target pixel index, or -1 if dropped (flow-only) ----
__device__ __forceinline__ int target_of(int y, int x, float fx, float fy) {
    int ty = (int)rintf((float)y + fy);  // rintf = round-half-even = jnp.round
    int tx = (int)rintf((float)x + fx);
    if (ty < 0) ty += HH;                // JAX normalizes negative indices once
    if (tx < 0) tx += WW;
    if ((unsigned)ty >= (unsigned)HH || (unsigned)tx >= (unsigned)WW) return -1;
    return ty * WW + tx;
}

// ---- level 1: LDS 4096-bin histogram of bits[31:20] + per-(block,tile) target counts ----
__global__ __launch_bounds__(BT) void k_histA_cnt(const float* __restrict__ depth,
                                                  const float* __restrict__ flow,
                                                  u32* __restrict__ tot1,
                                                  u32* __restrict__ tcnt) {
    __shared__ u32 h[4096];
    __shared__ u32 tc[NT512];
    int tid = threadIdx.x;
    for (int j = tid; j < 4096; j += BT) h[j] = 0;
    for (int j = tid; j < NT512; j += BT) tc[j] = 0;
    __syncthreads();
    const int nvec = NPIX / 4;
    for (int v = blockIdx.x * BT + tid; v < nvec; v += gridDim.x * BT) {
        int i = v * 4;
        float4 d4 = ((const float4*)depth)[v];
        float4 fa = ((const float4*)flow)[v * 2];
        float4 fb = ((const float4*)flow)[v * 2 + 1];
        int y = i / WW, x0 = i - y * WW;   // 4-group never crosses a row (WW%4==0)
        float dd[4] = {d4.x, d4.y, d4.z, d4.w};
        float fx[4] = {fa.x, fa.z, fb.x, fb.z};
        float fy[4] = {fa.y, fa.w, fb.y, fb.w};
        #pragma unroll
        for (int j = 0; j < 4; ++j) {
            if (dd[j] != 100.0f)                                   // sentinel excluded
                atomicAdd(&h[__float_as_uint(dd[j]) >> 20], 1u);   // d>0 -> monotonic bits
            int t = target_of(y, x0 + j, fx[j], fy[j]);
            if (t >= 0) {
                int ty = t / WW, tx = t - ty * WW;
                atomicAdd(&tc[(ty >> 6) * TCX + (tx >> 6)], 1u);
            }
        }
    }
    __syncthreads();
    u32 rep = blockIdx.x & (R1 - 1);
    for (int j = tid; j < 4096; j += BT) {
        u32 v = h[j];
        if (v) atomicAdd(&tot1[rep * 4096 + j], v);   // sparse, short chains
    }
    for (int j = tid; j < NT512; j += BT)
        tcnt[blockIdx.x * NT512 + j] = tc[j];         // non-atomic per-block counts
}

// ---- per-(tile, block) relative write bases (transposed) + per-tile totals ----
__global__ __launch_bounds__(NBLK) void k_tscan(const u32* __restrict__ tcnt,
                                                u32* __restrict__ ttot,
                                                u32* __restrict__ base2) {
    __shared__ u32 s[NBLK];
    int t = blockIdx.x, b = threadIdx.x;
    u32 v = tcnt[b * NT512 + t];
    s[b] = v;
    __syncthreads();
    for (int off = 1; off < NBLK; off <<= 1) {
        u32 x = (b >= off) ? s[b - off] : 0;
        __syncthreads();
        s[b] += x;
        __syncthreads();
    }
    base2[b * NT512 + t] = s[b] - v;     // [blk][tile]: coalesced read in scatter
    if (b == NBLK - 1) ttot[t] = s[NBLK - 1];
}

// ---- level-1 select + owner table + tile-total prefix sum ----
__global__ __launch_bounds__(1024) void k_selA(const u32* __restrict__ tot1,
                                               const int* __restrict__ splitp,
                                               const u32* __restrict__ ttot,
                                               u32* __restrict__ qb1, u32* __restrict__ qr1,
                                               u32* __restrict__ oidx, u32* __restrict__ obin,
                                               u32* __restrict__ nown,
                                               u32* __restrict__ tbase, u32* __restrict__ tend) {
    __shared__ u32 part[1024];
    __shared__ u32 qbS[NQ], qcS[NQ];
    __shared__ u32 totalsh;
    int tid = threadIdx.x;
    int split = *splitp;
    int base = tid * 4;
    u32 cc[4] = {0, 0, 0, 0};
    for (int r = 0; r < R1; ++r)
        for (int j = 0; j < 4; ++j) cc[j] += tot1[r * 4096 + base + j];
    u32 local = cc[0] + cc[1] + cc[2] + cc[3];
    part[tid] = local;
    __syncthreads();
    for (int off = 1; off < 1024; off <<= 1) {
        u32 v = (tid >= off) ? part[tid - off] : 0;
        __syncthreads();
        part[tid] += v;
        __syncthreads();
    }
    if (tid == 1023) totalsh = part[1023];
    __syncthreads();
    u32 l = totalsh;                 // valid-pixel count = histogram sum
    u32 step = l / (u32)split;
    u32 cum = part[tid] - local;     // exclusive prefix of this thread's 4 bins
    for (int j = 0; j < 4; ++j) {
        u32 c = cc[j];
        if (c) {
            for (int q = 0; q <= split; ++q) {
                u32 r = (q < split) ? (u32)q * step : l - 1u;
                if (r >= cum && r < cum + c) {
                    qb1[q] = (u32)(base + j);
                    qr1[q] = r - cum;
                    qbS[q] = (u32)(base + j);
                    qcS[q] = c;
                }
            }
        }
        cum += c;
    }
    __syncthreads();
    if (tid == 0) {   // owners: distinct (adjacent, ascending) hi-12 bins
        int w = -1;
        u32 prev = 0xFFFFFFFFu;
        for (int q = 0; q <= split; ++q) {
            if (qbS[q] != prev) { ++w; prev = qbS[q]; obin[w] = qbS[q]; }
            oidx[q] = (u32)w;
        }
        for (int w2 = w + 1; w2 < MAXOWN; ++w2) obin[w2] = 0xFFFFFFFFu;
        *nown = (u32)(w + 1);
    }
    __syncthreads();
    // ---- tile totals prefix sum -> tbase/tend ----
    u32 tv = (tid < NT512) ? ttot[tid] : 0;
    part[tid] = tv;
    __syncthreads();
    for (int off = 1; off < 1024; off <<= 1) {
        u32 v = (tid >= off) ? part[tid - off] : 0;
        __syncthreads();
        part[tid] += v;
        __syncthreads();
    }
    if (tid < NT512) {
        tbase[tid] = part[tid] - tv;
        tend[tid]  = part[tid];
    }
}

// ---- level 2: per-owner LDS hist of bits[19:10]; one block = (chunk, 4-owner group) ----
__global__ __launch_bounds__(1024) void k_ph1(const float* __restrict__ depth,
                                              const u32* __restrict__ obin,
                                              const u32* __restrict__ nownp,
                                              u32* __restrict__ ghist) {
    int c = blockIdx.x / NGRP;          // chunk
    int g = blockIdx.x % NGRP;          // owner group
    int w0 = g * OPB;
    int nown = (int)*nownp;
    if (w0 >= nown) return;
    __shared__ u32 h[OPB * 1024];       // 16 KB
    int tid = threadIdx.x;
    u32 ob[OPB];
    #pragma unroll
    for (int k = 0; k < OPB; ++k)
        ob[k] = (w0 + k < nown) ? obin[w0 + k] : 0xFFFFFFFFu;   // sentinel never matches
    for (int j = tid; j < OPB * 1024; j += 1024) h[j] = 0;
    __syncthreads();
    const int per = (NPIX / 4) / NCH1;  // 8100 float4 per chunk, exact
    int lo = c * per, hi = lo + per;
    for (int v = lo + tid; v < hi; v += 1024) {
        float4 d4 = ((const float4*)depth)[v];
        float dd[4] = {d4.x, d4.y, d4.z, d4.w};
        #pragma unroll
        for (int j = 0; j < 4; ++j) {
            u32 bits = __float_as_uint(dd[j]);
            u32 b1 = bits >> 20;
            #pragma unroll
            for (int k = 0; k < OPB; ++k)
                if (ob[k] == b1)
                    atomicAdd(&h[k * 1024 + ((bits >> 10) & 1023u)], 1u);
        }
    }
    __syncthreads();
    for (int j = tid; j < OPB * 1024; j += 1024) {
        int k = j >> 10, bin = j & 1023;
        int w = w0 + k;
        if (w < nown) ghist[(w * NCH1 + c) * 1024 + bin] = h[j];   // non-atomic chunk write
    }
}

// ---- level-2 reduce: chunks -> (key22, r2) per query ----
__global__ __launch_bounds__(1024) void k_red1(const int* __restrict__ splitp,
                                               const u32* __restrict__ qb1,
                                               const u32* __restrict__ qr1,
                                               const u32* __restrict__ oidx,
                                               const u32* __restrict__ ghist,
                                               u32* __restrict__ key22, u32* __restrict__ r2o) {
    int q = blockIdx.x;
    if (q > *splitp) return;
    int w = (int)oidx[q];
    __shared__ u32 part[1024];
    int tid = threadIdx.x;
    u32 local = 0;
    for (int c = 0; c < NCH1; ++c) local += ghist[(w * NCH1 + c) * 1024 + tid];
    part[tid] = local;
    __syncthreads();
    for (int off = 1; off < 1024; off <<= 1) {
        u32 v = (tid >= off) ? part[tid - off] : 0;
        __syncthreads();
        part[tid] += v;
        __syncthreads();
    }
    u32 target = qr1[q];
    u32 cum = part[tid] - local;
    if (local && target >= cum && target < cum + local) {
        key22[q] = (qb1[q] << 10) | (u32)tid;
        r2o[q] = target - cum;
    }
}

// ---- level 3: low-10-bit histogram restricted to 22-bit keys (tiny atomic count) ----
__global__ __launch_bounds__(256) void k_ph2(const float* __restrict__ depth,
                                             const int* __restrict__ splitp,
                                             const u32* __restrict__ key22,
                                             u32* __restrict__ gh2) {
    __shared__ u32 k22[NQ];
    int tid = threadIdx.x, split = *splitp;
    if (tid < NQ) k22[tid] = (tid <= split) ? key22[tid] : 0xFFFFFFFFu;
    __syncthreads();
    const int nvec = NPIX / 4;
    for (int v = blockIdx.x * blockDim.x + tid; v < nvec; v += gridDim.x * blockDim.x) {
        float4 d4 = ((const float4*)depth)[v];
        float dd[4] = {d4.x, d4.y, d4.z, d4.w};
        #pragma unroll
        for (int j = 0; j < 4; ++j) {
            if (dd[j] != 100.0f) {
                u32 bits = __float_as_uint(dd[j]);
                u32 hi22 = bits >> 10;
                for (int q = 0; q <= split; ++q)
                    if (k22[q] == hi22) atomicAdd(&gh2[q * 1024 + (bits & 1023u)], 1u);
            }
        }
    }
}

// ---- level-3 reduce: exact order-statistic floats ----
__global__ __launch_bounds__(1024) void k_red2(const int* __restrict__ splitp,
                                               const u32* __restrict__ key22,
                                               const u32* __restrict__ r2o,
                                               const u32* __restrict__ gh2,
                                               float* __restrict__ mids) {
    int q = blockIdx.x;
    if (q > *splitp) return;
    __shared__ u32 part[1024];
    int tid = threadIdx.x;
    u32 local = gh2[q * 1024 + tid];
    part[tid] = local;
    __syncthreads();
    for (int off = 1; off < 1024; off <<= 1) {
        u32 v = (tid >= off) ? part[tid - off] : 0;
        __syncthreads();
        part[tid] += v;
        __syncthreads();
    }
    u32 target = r2o[q];
    u32 cum = part[tid] - local;
    if (local && target >= cum && target < cum + local)
        mids[q] = __uint_as_float((key22[q] << 10) | (u32)tid);
}

// ---- scatter: exact-base pair writes, zero device atomics, no inner barriers ----
__global__ __launch_bounds__(BT) void k_scatter(const float* __restrict__ depth,
                                                const float* __restrict__ flow,
                                                const int* __restrict__ splitp,
                                                const float* __restrict__ mids,
                                                const u32* __restrict__ tbase,
                                                const u32* __restrict__ base2,
                                                uint2* __restrict__ pairs) {
    __shared__ u32 cur[NT512];
    __shared__ float msh[NQ];
    int tid = threadIdx.x, split = *splitp;
    if (tid < NQ) msh[tid] = (tid <= split) ? mids[tid] : 0.f;
    for (int j = tid; j < NT512; j += BT)
        cur[j] = tbase[j] + base2[blockIdx.x * NT512 + j];   // coalesced 2 KB read
    __syncthreads();
    const int nvec = NPIX / 4;   // traversal MUST match k_histA_cnt exactly
    for (int v = blockIdx.x * BT + tid; v < nvec; v += gridDim.x * BT) {
        int i = v * 4;
        float4 d4 = ((const float4*)depth)[v];
        float4 fa = ((const float4*)flow)[v * 2];
        float4 fb = ((const float4*)flow)[v * 2 + 1];
        int y = i / WW, x0 = i - y * WW;
        float dd[4] = {d4.x, d4.y, d4.z, d4.w};
        float fx[4] = {fa.x, fa.z, fb.x, fb.z};
        float fy[4] = {fa.y, fa.w, fb.y, fb.w};
        #pragma unroll
        for (int j = 0; j < 4; ++j) {
            int t = target_of(y, x0 + j, fx[j], fy[j]);
            if (t < 0) continue;                      // only this drop counted by histA too
            float d = dd[j];
            int rank = -1;
            for (int k = 1; k <= split; ++k)
                if (d >= msh[k - 1] && d < msh[k]) { rank = split - k; break; }
            // far bins = low rank; within bin, last row-major source wins.
            // rank<0 (d==max or sentinel): dummy p=0 keeps segments dense.
            u32 p = (rank >= 0) ? (u32)rank * (u32)NPIX + (u32)(i + j) + 1u : 0u;
            int ty = t / WW, tx = t - ty * WW;
            int tile = (ty >> 6) * TCX + (tx >> 6);
            u32 pos = atomicAdd(&cur[tile], 1u);      // LDS only
            pairs[pos] = make_uint2((u32)t, p);
        }
    }
}

// ---- per-tile LDS z-buffer reduce + output write ----
__global__ __launch_bounds__(1024) void k_tile_reduce(const uint2* __restrict__ pairs,
                                                      const u32* __restrict__ tbase,
                                                      const u32* __restrict__ tend,
                                                      const float* __restrict__ img,
                                                      float* __restrict__ out) {
    __shared__ u32 zb[TS * TS];
    int tid = threadIdx.x;
    int tile = blockIdx.x;
    for (int c = tid; c < TS * TS; c += 1024) zb[c] = 0;
    __syncthreads();
    int ty0 = (tile / TCX) << 6, tx0 = (tile % TCX) << 6;
    u32 b = tbase[tile], e = tend[tile];
    for (u32 k = b + tid; k < e; k += 1024) {
        uint2 pr = pairs[k];
        int t = (int)pr.x;
        int ty = t / WW, tx = t - ty * WW;
        atomicMax(&zb[((ty - ty0) << 6) | (tx - tx0)], pr.y);   // LDS
    }
    __syncthreads();
    for (int c = tid; c < TS * TS; c += 1024) {
        int ty = ty0 + (c >> 6);
        if (ty >= HH) continue;
        int tx = tx0 + (c & 63);
        u32 p = zb[c];
        float r = 0.f, g = 0.f, bl = 0.f;
        if (p) {
            u32 src = (p - 1u) % (u32)NPIX;   // p-1 = rank*NPIX + src
            r  = img[src * 3 + 0];
            g  = img[src * 3 + 1];
            bl = img[src * 3 + 2];
        }
        int t = ty * WW + tx;
        out[t * 3 + 0] = r;
        out[t * 3 + 1] = g;
        out[t * 3 + 2] = bl;
    }
}

extern "C" void kernel_launch(void* const* d_in, const int* in_sizes, int n_in,
                              void* d_out, int out_size, void* d_ws, size_t ws_size,
                              hipStream_t stream) {
    const float* img    = (const float*)d_in[0];
    const float* flow   = (const float*)d_in[1];   // [1,H,W,2] flat == [H,W,2]
    const float* depth  = (const float*)d_in[2];
    const int*   splitp = (const int*)d_in[3];

    char* ws = (char*)d_ws;
    float* mids  = (float*)(ws + MIDS_OFF);
    u32*   qb1   = (u32*)(ws + QB1_OFF);
    u32*   qr1   = (u32*)(ws + QR1_OFF);
    u32*   oidx  = (u32*)(ws + OIDX_OFF);
    u32*   obin  = (u32*)(ws + OBIN_OFF);
    u32*   nown  = (u32*)(ws + NOWN_OFF);
    u32*   key22 = (u32*)(ws + KEY22_OFF);
    u32*   r2o   = (u32*)(ws + R2O_OFF);
    u32*   tot1  = (u32*)(ws + TOT1_OFF);
    u32*   gh2   = (u32*)(ws + GH2_OFF);
    u32*   tcnt  = (u32*)(ws + TCNT_OFF);
    u32*   ttot  = (u32*)(ws + TTOT_OFF);
    u32*   tbase = (u32*)(ws + TBASE_OFF);
    u32*   tend  = (u32*)(ws + TEND_OFF);
    u32*   base2 = (u32*)(ws + BASE2_OFF);
    u32*   gh1   = (u32*)(ws + GH1_OFF);
    uint2* pairs = (uint2*)(ws + PAIRS_OFF);
    float* out   = (float*)d_out;

    // zero header + tot1 + gh2 with our own kernel (runtime small-fill was 41 us)
    k_zero       <<<ZBLK, 256, 0, stream>>>((float4*)d_ws);
    k_histA_cnt  <<<NBLK, BT, 0, stream>>>(depth, flow, tot1, tcnt);
    k_tscan      <<<NT512, NBLK, 0, stream>>>(tcnt, ttot, base2);
    k_selA       <<<1, 1024, 0, stream>>>(tot1, splitp, ttot, qb1, qr1, oidx, obin, nown, tbase, tend);
    k_ph1        <<<NCH1 * NGRP, 1024, 0, stream>>>(depth, obin, nown, gh1);
    k_red1       <<<NQ, 1024, 0, stream>>>(splitp, qb1, qr1, oidx, gh1, key22, r2o);
    k_ph2        <<<2048, 256, 0, stream>>>(depth, splitp, key22, gh2);
    k_red2       <<<NQ, 1024, 0, stream>>>(splitp, key22, r2o, gh2, mids);
    k_scatter    <<<NBLK, BT, 0, stream>>>(depth, flow, splitp, mids, tbase, base2, pairs);
    k_tile_reduce<<<NTILE, 1024, 0, stream>>>(pairs, tbase, tend, img, out);
}